// Round 2
// baseline (12359.251 us; speedup 1.0000x reference)
//
#include <hip/hip_runtime.h>
#include <cmath>

// Problem constants
#define B_ 128
#define T_ 256
#define F_ 1024
#define H_ 1024

typedef __bf16 bf16x8 __attribute__((ext_vector_type(8)));
typedef __bf16 bf16x4 __attribute__((ext_vector_type(4)));
typedef float f32x4 __attribute__((ext_vector_type(4)));

#define LDS_PAD 8
#define LDA (64 + LDS_PAD)  // 72 bf16 = 144 B row stride (16B aligned)

__device__ __forceinline__ float sigf(float v)  { return 1.0f / (1.0f + __expf(-v)); }
// NaN-free tanh: x->+inf => 1-2/inf = 1; x->-inf => 1-2/1 = -1
__device__ __forceinline__ float tanhfast(float x) { return 1.0f - 2.0f / (1.0f + __expf(2.0f * x)); }

// fp32 -> bf16 weight conversion (n must be a multiple of 8*256*gridDim)
__global__ void k_cvt(const float* __restrict__ src, __bf16* __restrict__ dst, int n) {
    int i = (blockIdx.x * 256 + threadIdx.x) * 8;
    if (i + 7 < n) {
        float4 a = *(const float4*)(src + i);
        float4 b = *(const float4*)(src + i + 4);
        bf16x8 o = { (__bf16)a.x, (__bf16)a.y, (__bf16)a.z, (__bf16)a.w,
                     (__bf16)b.x, (__bf16)b.y, (__bf16)b.z, (__bf16)b.w };
        *(bf16x8*)(dst + i) = o;
    }
}

__global__ void k_bias(const float* __restrict__ bi0, const float* __restrict__ bh0,
                       const float* __restrict__ bi1, const float* __restrict__ bh1,
                       float* __restrict__ bs0, float* __restrict__ bs1) {
    int j = blockIdx.x * 256 + threadIdx.x;  // 16 blocks x 256 = 4096
    bs0[j] = bi0[j] + bh0[j];
    bs1[j] = bi1[j] + bh1[j];
}

// Zero fp32 cell states and the "h at t=-1" bf16 buffers (ws is poisoned 0xAA).
__global__ void k_init(float* c0, float* c1, __bf16* h0b, __bf16* h1b) {
    int i = blockIdx.x * 256 + threadIdx.x;  // 512 blocks covers 131072
    c0[i] = 0.0f;
    c1[i] = 0.0f;
    h0b[i] = (__bf16)0.0f;
    h1b[i] = (__bf16)0.0f;
}

// One pipelined step: blocks [0,128) = cell0 @ t0 (if t0>=0), [128,256) = cell1 @ t1 (if t1>=0).
// cell0(t0) needs h0(t0-1); cell1(t1) needs h0(t1), h1(t1-1) -> independent when t0 = t1+1.
__global__ __launch_bounds__(256) void lstm_step(
    const float* __restrict__ x,
    const __bf16* __restrict__ Wb,   // preconverted [Wih0|Whh0|Wih1|Whh1] (4x 4096x1024) or unused
    const float* __restrict__ Wih0f, const float* __restrict__ Whh0f,
    const float* __restrict__ Wih1f, const float* __restrict__ Whh1f,
    const float* __restrict__ bs0, const float* __restrict__ bs1,
    __bf16* __restrict__ h0a, __bf16* __restrict__ h0b,
    __bf16* __restrict__ h1a, __bf16* __restrict__ h1b,
    float* __restrict__ c0, float* __restrict__ c1,
    float* __restrict__ out,
    int t0, int t1, int useWb)
{
    const int cell = blockIdx.x >> 7;
    const int bidx = blockIdx.x & 127;
    if (cell == 0 && t0 < 0) return;
    if (cell == 1 && t1 < 0) return;

    const int m0 = (bidx & 1) * 64;   // batch-row tile
    const int j0 = (bidx >> 1) * 16;  // h-column tile (x4 gates)

    // h parity: h at step t lives in (t&1 ? *b-buffer... ) convention:
    //   h0(t) in (t&1 ? h0b : h0a); h1(t) in (t&1 ? h1b : h1a).
    const float* bsum;
    const float *Wf_ih, *Wf_hh;
    long WbOff;                       // element offset of this cell's [Wih|Whh] in Wb
    const float*  a0f = nullptr;      // phase-0 A source when fp32 (cell0: x)
    const __bf16* a0b = nullptr;      // phase-0 A source when bf16 (cell1: h0)
    long a0stride;
    const __bf16* a1b;                // phase-1 A source (always bf16 h)
    float* cPtr;
    __bf16* hw;
    if (cell == 0) {
        WbOff = 0; Wf_ih = Wih0f; Wf_hh = Whh0f; bsum = bs0;
        a0f = x + (long)t0 * F_;  a0stride = (long)T_ * F_;
        a1b = (t0 & 1) ? h0a : h0b;   // h0(t0-1)
        hw  = (t0 & 1) ? h0b : h0a;   // h0(t0)
        cPtr = c0;
    } else {
        WbOff = 8388608; Wf_ih = Wih1f; Wf_hh = Whh1f; bsum = bs1;
        a0b = (t1 & 1) ? h0b : h0a;  a0stride = H_;   // h0(t1)
        a1b = (t1 & 1) ? h1a : h1b;                   // h1(t1-1)
        hw  = (t1 & 1) ? h1b : h1a;                   // h1(t1)
        cPtr = c1;
    }

    __shared__ __align__(16) __bf16 lsA[64 * LDA];
    __shared__ __align__(16) __bf16 lsB[64 * LDA];

    const int tid  = threadIdx.x;
    const int wave = tid >> 6;
    const int lane = tid & 63;
    const int quad = lane >> 4;
    const int lrow = lane & 15;

    f32x4 acc0 = {0.f, 0.f, 0.f, 0.f};
    f32x4 acc1 = {0.f, 0.f, 0.f, 0.f};
    f32x4 acc2 = {0.f, 0.f, 0.f, 0.f};
    f32x4 acc3 = {0.f, 0.f, 0.f, 0.f};

    // K = 2048: k in [0,1024) uses Wih/A0, k in [1024,2048) uses Whh/A1
    for (int kt = 0; kt < 2048; kt += 64) {
        const bool ph = kt >= 1024;
        const int kk = ph ? (kt - 1024) : kt;

        // ---- stage A tile (64 batch rows x 64 K) ----
        if (!ph && cell == 0) {
            // fp32 x, convert inline
            const float* src = a0f + kk;
            #pragma unroll
            for (int i = 0; i < 4; ++i) {
                int idx = tid + i * 256;          // [0,1024)
                int r = idx >> 4, s = idx & 15;   // r:[0,64) s:[0,16), 4 floats per chunk
                float4 v = *(const float4*)(src + (long)(m0 + r) * a0stride + s * 4);
                bf16x4 o = { (__bf16)v.x, (__bf16)v.y, (__bf16)v.z, (__bf16)v.w };
                *(bf16x4*)&lsA[r * LDA + s * 4] = o;
            }
        } else {
            // bf16 h source, stride 1024
            const __bf16* src = (ph ? a1b : a0b) + kk;
            #pragma unroll
            for (int i = 0; i < 2; ++i) {
                int idx = tid + i * 256;          // [0,512)
                int r = idx >> 3, s = idx & 7;    // 8 bf16 per chunk
                *(uint4*)&lsA[r * LDA + s * 8] =
                    *(const uint4*)(src + (long)(m0 + r) * 1024 + s * 8);
            }
        }

        // ---- stage B tile: rows (gate*16+g) hold W[gate*1024 + j0 + g][kk..kk+63] ----
        if (useWb) {
            const __bf16* src = Wb + WbOff + (ph ? 4194304 : 0) + kk;
            #pragma unroll
            for (int i = 0; i < 2; ++i) {
                int idx = tid + i * 256;
                int r = idx >> 3, s = idx & 7;
                int n = ((r >> 4) << 10) + j0 + (r & 15);
                *(uint4*)&lsB[r * LDA + s * 8] =
                    *(const uint4*)(src + (long)n * 1024 + s * 8);
            }
        } else {
            const float* src = (ph ? Wf_hh : Wf_ih) + kk;
            #pragma unroll
            for (int i = 0; i < 4; ++i) {
                int idx = tid + i * 256;
                int r = idx >> 4, s = idx & 15;
                int n = ((r >> 4) << 10) + j0 + (r & 15);
                float4 v = *(const float4*)(src + (long)n * 1024 + s * 4);
                bf16x4 o = { (__bf16)v.x, (__bf16)v.y, (__bf16)v.z, (__bf16)v.w };
                *(bf16x4*)&lsB[r * LDA + s * 4] = o;
            }
        }
        __syncthreads();

        #pragma unroll
        for (int ki = 0; ki < 64; ki += 32) {
            bf16x8 af = *(const bf16x8*)&lsA[(wave * 16 + lrow) * LDA + ki + quad * 8];
            bf16x8 b0 = *(const bf16x8*)&lsB[( 0 + lrow) * LDA + ki + quad * 8];
            bf16x8 b1 = *(const bf16x8*)&lsB[(16 + lrow) * LDA + ki + quad * 8];
            bf16x8 b2 = *(const bf16x8*)&lsB[(32 + lrow) * LDA + ki + quad * 8];
            bf16x8 b3 = *(const bf16x8*)&lsB[(48 + lrow) * LDA + ki + quad * 8];
            acc0 = __builtin_amdgcn_mfma_f32_16x16x32_bf16(af, b0, acc0, 0, 0, 0);
            acc1 = __builtin_amdgcn_mfma_f32_16x16x32_bf16(af, b1, acc1, 0, 0, 0);
            acc2 = __builtin_amdgcn_mfma_f32_16x16x32_bf16(af, b2, acc2, 0, 0, 0);
            acc3 = __builtin_amdgcn_mfma_f32_16x16x32_bf16(af, b3, acc3, 0, 0, 0);
        }
        __syncthreads();
    }

    // Epilogue: lane r holds gates for (b = m0 + wave*16 + quad*4 + r, j = j0 + lrow)
    const int j = j0 + lrow;
    const float bi = bsum[j];
    const float bf = bsum[1024 + j];
    const float bg = bsum[2048 + j];
    const float bo = bsum[3072 + j];

    const int tOut = (cell == 1) ? t1 : 0;
    #pragma unroll
    for (int r = 0; r < 4; ++r) {
        const int b = m0 + wave * 16 + quad * 4 + r;
        const float gi = sigf(acc0[r] + bi);
        const float gf = sigf(acc1[r] + bf);
        const float gg = tanhfast(acc2[r] + bg);
        const float go = sigf(acc3[r] + bo);
        const long idx = (long)b * H_ + j;
        const float cn = gf * cPtr[idx] + gi * gg;
        cPtr[idx] = cn;
        const float hn = go * tanhfast(cn);
        hw[idx] = (__bf16)hn;
        if (cell == 1) out[((long)b * T_ + tOut) * H_ + j] = hn;
    }
}

extern "C" void kernel_launch(void* const* d_in, const int* in_sizes, int n_in,
                              void* d_out, int out_size, void* d_ws, size_t ws_size,
                              hipStream_t stream)
{
    const float* x    = (const float*)d_in[0];
    const float* Wih0 = (const float*)d_in[1];
    const float* bih0 = (const float*)d_in[2];
    const float* Whh0 = (const float*)d_in[3];
    const float* bhh0 = (const float*)d_in[4];
    const float* Wih1 = (const float*)d_in[5];
    const float* bih1 = (const float*)d_in[6];
    const float* Whh1 = (const float*)d_in[7];
    const float* Whh1b= (const float*)d_in[7];
    const float* bhh1 = (const float*)d_in[8];
    float* out = (float*)d_out;

    // ws layout: [Wb bf16 32MiB (optional)] [bs0 16K][bs1 16K][c0 512K][c1 512K]
    //            [h0a 256K][h0b 256K][h1a 256K][h1b 256K]  -> 34.03 MiB (big) / 2.03 MiB (small)
    const bool big = ws_size >= ((size_t)36 << 20);
    char* ws = (char*)d_ws;
    __bf16* Wb = (__bf16*)ws;                      // only used when big
    size_t base = big ? ((size_t)32 << 20) : 0;
    float*  bs0 = (float*)(ws + base);
    float*  bs1 = (float*)(ws + base + (16 << 10));
    float*  c0  = (float*)(ws + base + (32 << 10));
    float*  c1  = (float*)(ws + base + (32 << 10) + (512 << 10));
    __bf16* h0a = (__bf16*)(ws + base + (32 << 10) + (1024 << 10));
    __bf16* h0b = (__bf16*)(ws + base + (32 << 10) + (1280 << 10));
    __bf16* h1a = (__bf16*)(ws + base + (32 << 10) + (1536 << 10));
    __bf16* h1b = (__bf16*)(ws + base + (32 << 10) + (1792 << 10));

    const int NW = 4194304;  // 4096*1024 elements per weight matrix
    if (big) {
        k_cvt<<<dim3(2048), dim3(256), 0, stream>>>(Wih0, Wb + 0L * NW, NW);
        k_cvt<<<dim3(2048), dim3(256), 0, stream>>>(Whh0, Wb + 1L * NW, NW);
        k_cvt<<<dim3(2048), dim3(256), 0, stream>>>(Wih1, Wb + 2L * NW, NW);
        k_cvt<<<dim3(2048), dim3(256), 0, stream>>>(Whh1b,Wb + 3L * NW, NW);
    }
    k_bias<<<dim3(16), dim3(256), 0, stream>>>(bih0, bhh0, bih1, bhh1, bs0, bs1);
    k_init<<<dim3(512), dim3(256), 0, stream>>>(c0, c1, h0b, h1b);

    const int useWb = big ? 1 : 0;

    // t=0: cell0 only
    lstm_step<<<dim3(256), dim3(256), 0, stream>>>(
        x, Wb, Wih0, Whh0, Wih1, Whh1, bs0, bs1,
        h0a, h0b, h1a, h1b, c0, c1, out, 0, -1, useWb);

    // pipelined: cell0(t+1) with cell1(t)
    for (int t = 0; t < T_ - 1; ++t) {
        lstm_step<<<dim3(256), dim3(256), 0, stream>>>(
            x, Wb, Wih0, Whh0, Wih1, Whh1, bs0, bs1,
            h0a, h0b, h1a, h1b, c0, c1, out, t + 1, t, useWb);
    }

    // final: cell1(T-1) only
    lstm_step<<<dim3(256), dim3(256), 0, stream>>>(
        x, Wb, Wih0, Whh0, Wih1, Whh1, bs0, bs1,
        h0a, h0b, h1a, h1b, c0, c1, out, -1, T_ - 1, useWb);

    (void)in_sizes; (void)n_in; (void)out_size;
}